// Round 2
// baseline (5649.338 us; speedup 1.0000x reference)
//
#include <hip/hip_runtime.h>

#define N_NODES 50000
#define N_EDGES 1600000
#define IN_DIM 512
#define OUT_DIM 256
#define TM 64     // rows per block in GEMM
#define KC 32     // k-chunk staged in LDS

// ---------------------------------------------------------------------------
// Kernel 1: out[n, c] = bias[c]   (scatter then adds on top; no finalize pass)
// ---------------------------------------------------------------------------
__global__ __launch_bounds__(256) void init_out(const float* __restrict__ bias,
                                                float* __restrict__ out) {
    const int i = blockIdx.x * blockDim.x + threadIdx.x;   // 4 floats per thread
    const int idx = i * 4;
    const int c = idx & (OUT_DIM - 1);
    *(float4*)(out + idx) = *(const float4*)(bias + c);
}

// ---------------------------------------------------------------------------
// Kernel 2: S = X @ W  (fp32, register-blocked: 64 rows x 256 cols per block,
// each thread computes 16 rows x 4 cols; W k-chunks staged in LDS)
// ---------------------------------------------------------------------------
__global__ __launch_bounds__(256, 4) void gemm_xw(const float* __restrict__ X,
                                                  const float* __restrict__ W,
                                                  float* __restrict__ S) {
    __shared__ float Ws[KC][OUT_DIM];      // 32 KB
    __shared__ float Xs[TM][KC + 4];       // 64*36*4 = 9.2 KB (pad keeps 16B align)

    const int tid  = threadIdx.x;
    const int r0   = blockIdx.x * TM;
    const int rowg = (tid >> 6) * 16;      // this thread's first row (within tile)
    const int colg = (tid & 63) * 4;       // this thread's first col

    float acc[16][4];
    #pragma unroll
    for (int i = 0; i < 16; ++i)
        #pragma unroll
        for (int j = 0; j < 4; ++j) acc[i][j] = 0.f;

    for (int kc = 0; kc < IN_DIM; kc += KC) {
        // stage W[kc:kc+32, 0:256] -> 2048 float4, 8 per thread, coalesced
        const float4* wg = (const float4*)(W + (size_t)kc * OUT_DIM);
        float4* wl = (float4*)&Ws[0][0];
        #pragma unroll
        for (int i = 0; i < 8; ++i) wl[tid + i * 256] = wg[tid + i * 256];

        // stage X[r0:r0+64, kc:kc+32] -> 512 float4, 2 per thread
        {
            const int rr = tid >> 3;           // 0..31
            const int cc = (tid & 7) * 4;      // 0..28
            #pragma unroll
            for (int i = 0; i < 2; ++i) {
                const int row = rr + i * 32;
                const int gr  = r0 + row;
                float4 xv = make_float4(0.f, 0.f, 0.f, 0.f);
                if (gr < N_NODES)
                    xv = *(const float4*)(X + (size_t)gr * IN_DIM + kc + cc);
                *(float4*)&Xs[row][cc] = xv;
            }
        }
        __syncthreads();

        #pragma unroll 4
        for (int k = 0; k < KC; ++k) {
            const float4 wv = *(const float4*)&Ws[k][colg];   // b128, 2-way = free
            float xr[16];
            #pragma unroll
            for (int i = 0; i < 16; ++i) xr[i] = Xs[rowg + i][k];  // wave-broadcast
            #pragma unroll
            for (int i = 0; i < 16; ++i) {
                acc[i][0] += xr[i] * wv.x;
                acc[i][1] += xr[i] * wv.y;
                acc[i][2] += xr[i] * wv.z;
                acc[i][3] += xr[i] * wv.w;
            }
        }
        __syncthreads();
    }

    #pragma unroll
    for (int i = 0; i < 16; ++i) {
        const int gr = r0 + rowg + i;
        if (gr < N_NODES) {
            float4 o = make_float4(acc[i][0], acc[i][1], acc[i][2], acc[i][3]);
            *(float4*)(S + (size_t)gr * OUT_DIM + colg) = o;
        }
    }
}

// ---------------------------------------------------------------------------
// Kernel 3: out[r] += val * S[c]  — one wave per edge, lane = 4 channels
// ---------------------------------------------------------------------------
__global__ __launch_bounds__(256) void spmm_scatter(const int* __restrict__ er,
                                                    const int* __restrict__ ec,
                                                    const float* __restrict__ ev,
                                                    const float* __restrict__ S,
                                                    float* __restrict__ out) {
    const long long gid = (long long)blockIdx.x * blockDim.x + threadIdx.x;
    const int e    = (int)(gid >> 6);
    const int lane = (int)(gid & 63);
    if (e >= N_EDGES) return;
    const int r   = er[e];
    const int c   = ec[e];
    const float v = ev[e];
    const float4 sv = *(const float4*)(S + (size_t)c * OUT_DIM + lane * 4);
    float* dst = out + (size_t)r * OUT_DIM + lane * 4;
    atomicAdd(dst + 0, v * sv.x);
    atomicAdd(dst + 1, v * sv.y);
    atomicAdd(dst + 2, v * sv.z);
    atomicAdd(dst + 3, v * sv.w);
}

extern "C" void kernel_launch(void* const* d_in, const int* in_sizes, int n_in,
                              void* d_out, int out_size, void* d_ws, size_t ws_size,
                              hipStream_t stream) {
    const float* X    = (const float*)d_in[0];   // [N_NODES, IN_DIM] fp32
    const int*   er   = (const int*)d_in[1];     // [N_EDGES] int32
    const int*   ec   = (const int*)d_in[2];     // [N_EDGES] int32
    const float* ev   = (const float*)d_in[3];   // [N_EDGES] fp32
    const float* W    = (const float*)d_in[4];   // [IN_DIM, OUT_DIM] fp32
    const float* bias = (const float*)d_in[5];   // [OUT_DIM] fp32
    float* out        = (float*)d_out;           // [N_NODES, OUT_DIM] fp32

    float* S = (float*)d_ws;                     // [N_NODES, OUT_DIM] fp32 = 51.2 MB

    const int n4 = N_NODES * OUT_DIM / 4;        // 3.2M float4 groups

    hipLaunchKernelGGL(init_out, dim3(n4 / 256), dim3(256), 0, stream, bias, out);
    hipLaunchKernelGGL(gemm_xw, dim3((N_NODES + TM - 1) / TM), dim3(256), 0, stream,
                       X, W, S);
    hipLaunchKernelGGL(spmm_scatter, dim3(N_EDGES * 64 / 256), dim3(256), 0, stream,
                       er, ec, ev, S, out);
}

// Round 3
// 864.591 us; speedup vs baseline: 6.5341x; 6.5341x over previous
//
#include <hip/hip_runtime.h>

#define N_NODES 50000
#define N_EDGES 1600000
#define IN_DIM 512
#define OUT_DIM 256
#define TM 64     // rows per block in GEMM
#define KC 32     // k-chunk staged in LDS

// ---------------------------------------------------------------------------
// ws layout (bytes, 16-aligned):
//   S        [0,            51,200,000)  fp32 [50000,256] support
//   scol     [51,200,000,   57,600,000)  int  [1.6M] row-sorted cols
//   sval     [57,600,000,   64,000,000)  fp32 [1.6M] row-sorted vals
//   cnt      [64,000,000,   64,200,000)  int  [50000] per-row edge counts
//   row_ptr  [64,200,000,   64,400,016)  int  [50001]
//   cursor   [64,400,016,   64,600,016)  int  [50000] bucket cursors
// total ~64.6 MB
// ---------------------------------------------------------------------------

// Kernel A: zero the histogram counters
__global__ __launch_bounds__(256) void zero_cnt(int* __restrict__ cnt) {
    const int i = blockIdx.x * blockDim.x + threadIdx.x;
    if (i < N_NODES) cnt[i] = 0;
}

// Kernel B: histogram of edge_row
__global__ __launch_bounds__(256) void hist(const int* __restrict__ er,
                                            int* __restrict__ cnt) {
    const int e = blockIdx.x * blockDim.x + threadIdx.x;
    if (e < N_EDGES) atomicAdd(&cnt[er[e]], 1);
}

// Kernel C: exclusive scan of cnt -> row_ptr (and cursor copy), single block
__global__ __launch_bounds__(1024) void scan(const int* __restrict__ cnt,
                                             int* __restrict__ row_ptr,
                                             int* __restrict__ cursor) {
    __shared__ int sums[1024];
    const int tid = threadIdx.x;
    const int per = (N_NODES + 1023) / 1024;     // 49
    const int base = tid * per;

    int s = 0;
    for (int i = 0; i < per; ++i) {
        const int idx = base + i;
        if (idx < N_NODES) s += cnt[idx];
    }
    sums[tid] = s;
    __syncthreads();
    // Hillis-Steele inclusive scan over 1024 partials
    for (int off = 1; off < 1024; off <<= 1) {
        const int t = (tid >= off) ? sums[tid - off] : 0;
        __syncthreads();
        sums[tid] += t;
        __syncthreads();
    }
    int prefix = sums[tid] - s;                   // exclusive prefix for this chunk
    for (int i = 0; i < per; ++i) {
        const int idx = base + i;
        if (idx < N_NODES) {
            row_ptr[idx] = prefix;
            cursor[idx]  = prefix;
            prefix += cnt[idx];
        }
    }
    if (tid == 0) row_ptr[N_NODES] = N_EDGES;
}

// Kernel D: bucket edges into row-sorted order
__global__ __launch_bounds__(256) void bucket(const int* __restrict__ er,
                                              const int* __restrict__ ec,
                                              const float* __restrict__ ev,
                                              int* __restrict__ cursor,
                                              int* __restrict__ scol,
                                              float* __restrict__ sval) {
    const int e = blockIdx.x * blockDim.x + threadIdx.x;
    if (e >= N_EDGES) return;
    const int r = er[e];
    const int pos = atomicAdd(&cursor[r], 1);
    scol[pos] = ec[e];
    sval[pos] = ev[e];
}

// ---------------------------------------------------------------------------
// Kernel 2: S = X @ W  (fp32, register-blocked — unchanged from round 2)
// ---------------------------------------------------------------------------
__global__ __launch_bounds__(256, 4) void gemm_xw(const float* __restrict__ X,
                                                  const float* __restrict__ W,
                                                  float* __restrict__ S) {
    __shared__ float Ws[KC][OUT_DIM];      // 32 KB
    __shared__ float Xs[TM][KC + 4];       // 9.2 KB

    const int tid  = threadIdx.x;
    const int r0   = blockIdx.x * TM;
    const int rowg = (tid >> 6) * 16;
    const int colg = (tid & 63) * 4;

    float acc[16][4];
    #pragma unroll
    for (int i = 0; i < 16; ++i)
        #pragma unroll
        for (int j = 0; j < 4; ++j) acc[i][j] = 0.f;

    for (int kc = 0; kc < IN_DIM; kc += KC) {
        const float4* wg = (const float4*)(W + (size_t)kc * OUT_DIM);
        float4* wl = (float4*)&Ws[0][0];
        #pragma unroll
        for (int i = 0; i < 8; ++i) wl[tid + i * 256] = wg[tid + i * 256];
        {
            const int rr = tid >> 3;
            const int cc = (tid & 7) * 4;
            #pragma unroll
            for (int i = 0; i < 2; ++i) {
                const int row = rr + i * 32;
                const int gr  = r0 + row;
                float4 xv = make_float4(0.f, 0.f, 0.f, 0.f);
                if (gr < N_NODES)
                    xv = *(const float4*)(X + (size_t)gr * IN_DIM + kc + cc);
                *(float4*)&Xs[row][cc] = xv;
            }
        }
        __syncthreads();

        #pragma unroll 4
        for (int k = 0; k < KC; ++k) {
            const float4 wv = *(const float4*)&Ws[k][colg];
            float xr[16];
            #pragma unroll
            for (int i = 0; i < 16; ++i) xr[i] = Xs[rowg + i][k];
            #pragma unroll
            for (int i = 0; i < 16; ++i) {
                acc[i][0] += xr[i] * wv.x;
                acc[i][1] += xr[i] * wv.y;
                acc[i][2] += xr[i] * wv.z;
                acc[i][3] += xr[i] * wv.w;
            }
        }
        __syncthreads();
    }

    #pragma unroll
    for (int i = 0; i < 16; ++i) {
        const int gr = r0 + rowg + i;
        if (gr < N_NODES) {
            float4 o = make_float4(acc[i][0], acc[i][1], acc[i][2], acc[i][3]);
            *(float4*)(S + (size_t)gr * OUT_DIM + colg) = o;
        }
    }
}

// ---------------------------------------------------------------------------
// Kernel E: out[r] = bias + sum_{e in row r} val[e] * S[col[e]]
// one wave per row; lane = 4 channels; 64-edge batches broadcast via shfl
// ---------------------------------------------------------------------------
__global__ __launch_bounds__(256) void csr_spmm(const int* __restrict__ row_ptr,
                                                const int* __restrict__ scol,
                                                const float* __restrict__ sval,
                                                const float* __restrict__ S,
                                                const float* __restrict__ bias,
                                                float* __restrict__ out) {
    const int wave = threadIdx.x >> 6;
    const int lane = threadIdx.x & 63;
    const int r = blockIdx.x * 4 + wave;
    if (r >= N_NODES) return;

    const int start = row_ptr[r];
    const int end   = row_ptr[r + 1];

    float4 acc = *(const float4*)(bias + lane * 4);

    for (int e0 = start; e0 < end; e0 += 64) {
        const int rem = end - e0;
        int   c = 0;
        float v = 0.f;
        if (lane < rem) {
            c = scol[e0 + lane];
            v = sval[e0 + lane];
        }
        const int n = rem < 64 ? rem : 64;
        for (int j = 0; j < n; ++j) {
            const int   cj = __shfl(c, j);
            const float vj = __shfl(v, j);
            const float4 sv = *(const float4*)(S + (size_t)cj * OUT_DIM + lane * 4);
            acc.x += vj * sv.x;
            acc.y += vj * sv.y;
            acc.z += vj * sv.z;
            acc.w += vj * sv.w;
        }
    }
    *(float4*)(out + (size_t)r * OUT_DIM + lane * 4) = acc;
}

extern "C" void kernel_launch(void* const* d_in, const int* in_sizes, int n_in,
                              void* d_out, int out_size, void* d_ws, size_t ws_size,
                              hipStream_t stream) {
    const float* X    = (const float*)d_in[0];
    const int*   er   = (const int*)d_in[1];
    const int*   ec   = (const int*)d_in[2];
    const float* ev   = (const float*)d_in[3];
    const float* W    = (const float*)d_in[4];
    const float* bias = (const float*)d_in[5];
    float* out        = (float*)d_out;

    char* ws = (char*)d_ws;
    float* S       = (float*)(ws);
    int*   scol    = (int*)  (ws + 51200000);
    float* sval    = (float*)(ws + 57600000);
    int*   cnt     = (int*)  (ws + 64000000);
    int*   row_ptr = (int*)  (ws + 64200000);
    int*   cursor  = (int*)  (ws + 64400016);

    hipLaunchKernelGGL(zero_cnt, dim3((N_NODES + 255) / 256), dim3(256), 0, stream,
                       cnt);
    hipLaunchKernelGGL(hist, dim3(N_EDGES / 256), dim3(256), 0, stream, er, cnt);
    hipLaunchKernelGGL(scan, dim3(1), dim3(1024), 0, stream, cnt, row_ptr, cursor);
    hipLaunchKernelGGL(bucket, dim3(N_EDGES / 256), dim3(256), 0, stream,
                       er, ec, ev, cursor, scol, sval);
    hipLaunchKernelGGL(gemm_xw, dim3((N_NODES + TM - 1) / TM), dim3(256), 0, stream,
                       X, W, S);
    hipLaunchKernelGGL(csr_spmm, dim3((N_NODES + 3) / 4), dim3(256), 0, stream,
                       row_ptr, scol, sval, S, bias, out);
}

// Round 4
// 509.309 us; speedup vs baseline: 11.0922x; 1.6976x over previous
//
#include <hip/hip_runtime.h>

#define N_NODES 50000
#define N_EDGES 1600000
#define IN_DIM 512
#define OUT_DIM 256

#define BM 128
#define BN 128
#define BK 32
#define APAD 8                 // pad rows to 40 shorts = 80 B -> 2-way banks (free)
#define LDA (BK + APAD)

typedef unsigned int u32;
typedef unsigned short u16;
typedef short bf16x8 __attribute__((ext_vector_type(8)));
typedef float f32x4 __attribute__((ext_vector_type(4)));

__device__ __forceinline__ float bf_to_f(u16 u) { return __uint_as_float(((u32)u) << 16); }
__device__ __forceinline__ u16 f_to_bf(float f) {
    u32 u = __float_as_uint(f);
    u32 r = (u + 0x7fffu + ((u >> 16) & 1u)) >> 16;   // RNE
    return (u16)r;
}

// ---------------------------------------------------------------------------
// CSR build
// ---------------------------------------------------------------------------
__global__ __launch_bounds__(256) void zero_cnt(int* __restrict__ cnt) {
    const int i = blockIdx.x * blockDim.x + threadIdx.x;
    if (i < N_NODES) cnt[i] = 0;
}

__global__ __launch_bounds__(256) void hist(const int* __restrict__ er,
                                            int* __restrict__ cnt) {
    const int e = blockIdx.x * blockDim.x + threadIdx.x;
    if (e < N_EDGES) atomicAdd(&cnt[er[e]], 1);
}

// pass 1: per-block (256-wide) exclusive scan; block totals to bsum
__global__ __launch_bounds__(256) void scan1(const int* __restrict__ cnt,
                                             int* __restrict__ row_ptr,
                                             int* __restrict__ bsum) {
    __shared__ int sh[256];
    const int t = threadIdx.x;
    const int i = blockIdx.x * 256 + t;
    const int v = (i < N_NODES) ? cnt[i] : 0;
    sh[t] = v;
    __syncthreads();
    #pragma unroll
    for (int off = 1; off < 256; off <<= 1) {
        const int tv = (t >= off) ? sh[t - off] : 0;
        __syncthreads();
        sh[t] += tv;
        __syncthreads();
    }
    if (i < N_NODES) row_ptr[i] = sh[t] - v;          // block-local exclusive
    if (t == 255) bsum[blockIdx.x] = sh[255];
}

// pass 2: scan the 196 block sums (single block)
__global__ __launch_bounds__(256) void scan2(int* __restrict__ bsum, int nb) {
    __shared__ int sh[256];
    const int t = threadIdx.x;
    const int v = (t < nb) ? bsum[t] : 0;
    sh[t] = v;
    __syncthreads();
    #pragma unroll
    for (int off = 1; off < 256; off <<= 1) {
        const int tv = (t >= off) ? sh[t - off] : 0;
        __syncthreads();
        sh[t] += tv;
        __syncthreads();
    }
    if (t < nb) bsum[t] = sh[t] - v;                  // exclusive block prefix
}

// pass 3: add block prefix; produce row_ptr + cursor
__global__ __launch_bounds__(256) void scan3(int* __restrict__ row_ptr,
                                             const int* __restrict__ bsum,
                                             int* __restrict__ cursor) {
    const int t = threadIdx.x;
    const int i = blockIdx.x * 256 + t;
    if (i < N_NODES) {
        const int r = row_ptr[i] + bsum[blockIdx.x];
        row_ptr[i] = r;
        cursor[i]  = r;
    }
    if (blockIdx.x == 0 && t == 0) row_ptr[N_NODES] = N_EDGES;
}

// bucket edges into row-sorted order; (col, valbits) packed as int2
__global__ __launch_bounds__(256) void bucket(const int* __restrict__ er,
                                              const int* __restrict__ ec,
                                              const float* __restrict__ ev,
                                              int* __restrict__ cursor,
                                              int2* __restrict__ sedge) {
    const int e = blockIdx.x * blockDim.x + threadIdx.x;
    if (e >= N_EDGES) return;
    const int r = er[e];
    const int pos = atomicAdd(&cursor[r], 1);
    sedge[pos] = make_int2(ec[e], __float_as_int(ev[e]));
}

// ---------------------------------------------------------------------------
// W [512,256] fp32  ->  WT [256,512] bf16 (transposed, K-contiguous)
// block handles 4 k-rows x 256 n; reads coalesced, writes ushort4
// ---------------------------------------------------------------------------
__global__ __launch_bounds__(256) void wcvt(const float* __restrict__ W,
                                            u16* __restrict__ WT) {
    const int n  = threadIdx.x;
    const int k0 = blockIdx.x * 4;
    ushort4 o;
    o.x = f_to_bf(W[(size_t)(k0 + 0) * OUT_DIM + n]);
    o.y = f_to_bf(W[(size_t)(k0 + 1) * OUT_DIM + n]);
    o.z = f_to_bf(W[(size_t)(k0 + 2) * OUT_DIM + n]);
    o.w = f_to_bf(W[(size_t)(k0 + 3) * OUT_DIM + n]);
    *(ushort4*)(WT + (size_t)n * IN_DIM + k0) = o;
}

// ---------------------------------------------------------------------------
// GEMM: Sb[M,256] = bf16( X[M,512] @ W[512,256] ), MFMA 16x16x32 bf16
// block = 256 thr = 4 waves; tile 128x128; wave computes 64x64 (4x4 tiles)
// A-staging converts fp32 X -> bf16 LDS on the fly; B comes from WT (bf16)
// ---------------------------------------------------------------------------
__global__ __launch_bounds__(256) void gemm_mfma(const float* __restrict__ X,
                                                 const u16* __restrict__ WT,
                                                 u16* __restrict__ Sb) {
    __shared__ u16 As[BM * LDA];   // [m][k] k-contiguous, 10 KB
    __shared__ u16 Bs[BN * LDA];   // [n][k] k-contiguous, 10 KB

    const int tid  = threadIdx.x;
    const int wave = tid >> 6;
    const int lane = tid & 63;
    const int r0   = blockIdx.x * BM;
    const int n0   = blockIdx.y * BN;
    const int wm   = (wave & 1) * 64;
    const int wn   = (wave >> 1) * 64;
    const int l15  = lane & 15;
    const int quad = lane >> 4;

    f32x4 acc[4][4];
    #pragma unroll
    for (int i = 0; i < 4; ++i)
        #pragma unroll
        for (int j = 0; j < 4; ++j) acc[i][j] = (f32x4)0.f;

    // staging coords: thread -> (row = tid>>1, kpart = (tid&1)*16)
    const int srow = tid >> 1;
    const int skp  = (tid & 1) * 16;
    // clamp X row so the last block never reads OOB (stores are masked)
    const int xrow = min(r0 + srow, N_NODES - 1);
    const float* xsrc = X + (size_t)xrow * IN_DIM + skp;
    const u16*   bsrc = WT + (size_t)(n0 + srow) * IN_DIM + skp;

    for (int kc = 0; kc < IN_DIM; kc += BK) {
        // ---- stage A: 16 fp32 -> 16 bf16 per thread
        {
            const float4 f0 = *(const float4*)(xsrc + kc + 0);
            const float4 f1 = *(const float4*)(xsrc + kc + 4);
            const float4 f2 = *(const float4*)(xsrc + kc + 8);
            const float4 f3 = *(const float4*)(xsrc + kc + 12);
            ushort4 p0, p1, p2, p3;
            p0.x = f_to_bf(f0.x); p0.y = f_to_bf(f0.y); p0.z = f_to_bf(f0.z); p0.w = f_to_bf(f0.w);
            p1.x = f_to_bf(f1.x); p1.y = f_to_bf(f1.y); p1.z = f_to_bf(f1.z); p1.w = f_to_bf(f1.w);
            p2.x = f_to_bf(f2.x); p2.y = f_to_bf(f2.y); p2.z = f_to_bf(f2.z); p2.w = f_to_bf(f2.w);
            p3.x = f_to_bf(f3.x); p3.y = f_to_bf(f3.y); p3.z = f_to_bf(f3.z); p3.w = f_to_bf(f3.w);
            *(ushort4*)&As[srow * LDA + skp + 0]  = p0;
            *(ushort4*)&As[srow * LDA + skp + 4]  = p1;
            *(ushort4*)&As[srow * LDA + skp + 8]  = p2;
            *(ushort4*)&As[srow * LDA + skp + 12] = p3;
        }
        // ---- stage B: 16 bf16 per thread (already converted)
        {
            const uint4 b0 = *(const uint4*)(bsrc + kc);      // 8 bf16
            const uint4 b1 = *(const uint4*)(bsrc + kc + 8);  // 8 bf16
            *(uint4*)&Bs[srow * LDA + skp + 0] = b0;
            *(uint4*)&Bs[srow * LDA + skp + 8] = b1;
        }
        __syncthreads();

        bf16x8 af[4], bf[4];
        #pragma unroll
        for (int mt = 0; mt < 4; ++mt)
            af[mt] = *(const bf16x8*)&As[(wm + mt * 16 + l15) * LDA + quad * 8];
        #pragma unroll
        for (int nt = 0; nt < 4; ++nt)
            bf[nt] = *(const bf16x8*)&Bs[(wn + nt * 16 + l15) * LDA + quad * 8];
        #pragma unroll
        for (int mt = 0; mt < 4; ++mt)
            #pragma unroll
            for (int nt = 0; nt < 4; ++nt)
                acc[mt][nt] = __builtin_amdgcn_mfma_f32_16x16x32_bf16(
                    af[mt], bf[nt], acc[mt][nt], 0, 0, 0);
        __syncthreads();
    }

    // epilogue: D[row = quad*4 + r][col = l15] per 16x16 tile
    #pragma unroll
    for (int mt = 0; mt < 4; ++mt) {
        #pragma unroll
        for (int r = 0; r < 4; ++r) {
            const int grow = r0 + wm + mt * 16 + quad * 4 + r;
            if (grow < N_NODES) {
                u16* dst = Sb + (size_t)grow * OUT_DIM + n0 + wn + l15;
                #pragma unroll
                for (int nt = 0; nt < 4; ++nt)
                    dst[nt * 16] = f_to_bf(acc[mt][nt][r]);
            }
        }
    }
}

// ---------------------------------------------------------------------------
// out[r] = bias + sum_{e in row r} val[e] * Sb[col[e]]   (bf16 gather, fp32 acc)
// one wave per row; lane = 4 channels; 64-edge batches broadcast via shfl
// ---------------------------------------------------------------------------
__global__ __launch_bounds__(256) void csr_spmm(const int* __restrict__ row_ptr,
                                                const int2* __restrict__ sedge,
                                                const u16* __restrict__ Sb,
                                                const float* __restrict__ bias,
                                                float* __restrict__ out) {
    const int wave = threadIdx.x >> 6;
    const int lane = threadIdx.x & 63;
    const int r = blockIdx.x * 4 + wave;
    if (r >= N_NODES) return;

    const int start = row_ptr[r];
    const int end   = row_ptr[r + 1];

    float4 acc = *(const float4*)(bias + lane * 4);

    int e0 = start;
    for (; e0 + 64 <= end; e0 += 64) {
        const int2 ev2 = sedge[e0 + lane];
        const int   c = ev2.x;
        const float v = __int_as_float(ev2.y);
        #pragma unroll 8
        for (int j = 0; j < 64; ++j) {
            const int   cj = __shfl(c, j);
            const float vj = __shfl(v, j);
            const ushort4 sv = *(const ushort4*)(Sb + (size_t)cj * OUT_DIM + lane * 4);
            acc.x += vj * bf_to_f(sv.x);
            acc.y += vj * bf_to_f(sv.y);
            acc.z += vj * bf_to_f(sv.z);
            acc.w += vj * bf_to_f(sv.w);
        }
    }
    if (e0 < end) {
        const int rem = end - e0;
        int   c = 0;
        float v = 0.f;
        if (lane < rem) {
            const int2 ev2 = sedge[e0 + lane];
            c = ev2.x;
            v = __int_as_float(ev2.y);
        }
        for (int j = 0; j < rem; ++j) {
            const int   cj = __shfl(c, j);
            const float vj = __shfl(v, j);
            const ushort4 sv = *(const ushort4*)(Sb + (size_t)cj * OUT_DIM + lane * 4);
            acc.x += vj * bf_to_f(sv.x);
            acc.y += vj * bf_to_f(sv.y);
            acc.z += vj * bf_to_f(sv.z);
            acc.w += vj * bf_to_f(sv.w);
        }
    }
    *(float4*)(out + (size_t)r * OUT_DIM + lane * 4) = acc;
}

extern "C" void kernel_launch(void* const* d_in, const int* in_sizes, int n_in,
                              void* d_out, int out_size, void* d_ws, size_t ws_size,
                              hipStream_t stream) {
    const float* X    = (const float*)d_in[0];
    const int*   er   = (const int*)d_in[1];
    const int*   ec   = (const int*)d_in[2];
    const float* ev   = (const float*)d_in[3];
    const float* W    = (const float*)d_in[4];
    const float* bias = (const float*)d_in[5];
    float* out        = (float*)d_out;

    // ws layout (~39.3 MB total)
    char* ws = (char*)d_ws;
    u16*  Sb      = (u16*) (ws);                       // 25,600,000 B
    u16*  WT      = (u16*) (ws + 25600000);            //    262,144 B
    int2* sedge   = (int2*)(ws + 25862144);            // 12,800,000 B
    int*  cnt     = (int*) (ws + 38662144);            //    200,000 B
    int*  row_ptr = (int*) (ws + 38862144);            //    200,004 B
    int*  cursor  = (int*) (ws + 39062160);            //    200,000 B
    int*  bsum    = (int*) (ws + 39262160);            //        784 B

    const int nb = (N_NODES + 255) / 256;              // 196

    hipLaunchKernelGGL(zero_cnt, dim3(nb), dim3(256), 0, stream, cnt);
    hipLaunchKernelGGL(hist, dim3(N_EDGES / 256), dim3(256), 0, stream, er, cnt);
    hipLaunchKernelGGL(scan1, dim3(nb), dim3(256), 0, stream, cnt, row_ptr, bsum);
    hipLaunchKernelGGL(scan2, dim3(1), dim3(256), 0, stream, bsum, nb);
    hipLaunchKernelGGL(scan3, dim3(nb), dim3(256), 0, stream, row_ptr, bsum, cursor);
    hipLaunchKernelGGL(bucket, dim3(N_EDGES / 256), dim3(256), 0, stream,
                       er, ec, ev, cursor, sedge);
    hipLaunchKernelGGL(wcvt, dim3(IN_DIM / 4), dim3(256), 0, stream, W, WT);
    hipLaunchKernelGGL(gemm_mfma, dim3((N_NODES + BM - 1) / BM, OUT_DIM / BN),
                       dim3(256), 0, stream, X, WT, Sb);
    hipLaunchKernelGGL(csr_spmm, dim3((N_NODES + 3) / 4), dim3(256), 0, stream,
                       row_ptr, sedge, Sb, bias, out);
}